// Round 13
// baseline (1828.817 us; speedup 1.0000x reference)
//
#include <hip/hip_runtime.h>
#include <math.h>
#include <stdint.h>

#define B 1024
#define H 512
#define T_SRC 50
#define T_TGT 30
#define I_DIM 4
#define NTHR 256

typedef _Float16 half8 __attribute__((ext_vector_type(8)));
typedef float f32x4 __attribute__((ext_vector_type(4)));
typedef unsigned long long u64;

#define GLOBAL_AS __attribute__((address_space(1)))
#define LDS_AS    __attribute__((address_space(3)))

#define SCALE_F 1099511627776.0f          // 2^40 (head fixed-point)
#define RING_BYTES 49152                  // 3 x 16KB ring
#define TRASH_OFF  RING_BYTES             // 4KB LDS trash for touch-prefetch
#define SMEM_BYTES (RING_BYTES + 4096)

__device__ __forceinline__ float sigm(float x) { return 1.0f / (1.0f + expf(-x)); }

// XCD-pinned mapping (r12-verified): blocks sharing a weight slice (ntile)
// land on one XCD (bx%8 round-robin heuristic; correctness unaffected).
__device__ __forceinline__ void sub_map(int sub, int& m0, int& kc0, int& ntile)
{
    const int xcd = sub & 7, j = sub >> 3;
    ntile = xcd * 4 + (j >> 4);
    const int g = j & 15;
    m0 = g * 64;
    kc0 = ntile * 16;
}

// ---------------- GEMM+cell core: r12-verified counted-vmcnt 3-ring, plus
// touch-prefetch: before the ring, issue global_load_lds of all B lines (both
// passes) + pass-1 A lines into an LDS trash slot. Touches are the OLDEST
// vmem ops; vmcnt retires in order (m135), so the ring's vmcnt(4) waits are
// unchanged in meaning ("tile t landed"), and tiles 2..nt-1 become L2 hits.
// Outstanding cap: 48 touches + 12 ring prologue = 60 <= 63. No VGPR dest ->
// no register-clobber hazard.
__device__ __forceinline__ void layer_core(
    char* smem,
    const _Float16* __restrict__ A1, const _Float16* __restrict__ W1,
    const _Float16* __restrict__ A2, const _Float16* __restrict__ W2,
    int npass, int zero_c,
    const float* __restrict__ xg, int xstride,
    const float* __restrict__ xl,
    const float* __restrict__ Wih,
    const float* __restrict__ bias,
    float* __restrict__ c_st, _Float16* __restrict__ h_out,
    _Float16* pH,
    int m0, int kc0)
{
    const int tid = threadIdx.x;
    const int w = tid >> 6, l = tid & 63;
    const int mw = (w & 1) * 32, nw = (w >> 1) * 32;

    f32x4 acc[2][2] = {};
    const int nt = npass * 8;

    size_t aoff[2], boff[2];
    int ldsw[2];
#pragma unroll
    for (int q = 0; q < 2; ++q) {
        int rowq = (w * 2 + q) * 8 + (l >> 3);
        int gsrc = (l & 7) ^ (rowq & 7);
        aoff[q] = (size_t)(m0 + rowq) * H + gsrc * 8;
        int jg = (rowq >> 4) * H + kc0 + (rowq & 15);
        boff[q] = (size_t)jg * H + gsrc * 8;
        ldsw[q] = (w * 2 + q) * 1024;
    }

    auto issue = [&](int t, int buf) {
        const _Float16* Ap = (t < 8) ? A1 : A2;
        const _Float16* Wp = (t < 8) ? W1 : W2;
        const int koff = (t & 7) * 64;
        char* dbase = smem + buf * 16384;
#pragma unroll
        for (int q = 0; q < 2; ++q) {
            __builtin_amdgcn_global_load_lds(
                (const GLOBAL_AS uint32_t*)(Ap + aoff[q] + koff),
                (LDS_AS uint32_t*)(dbase + ldsw[q]), 16, 0, 0);
            __builtin_amdgcn_global_load_lds(
                (const GLOBAL_AS uint32_t*)(Wp + boff[q] + koff),
                (LDS_AS uint32_t*)(dbase + 8192 + ldsw[q]), 16, 0, 0);
        }
    };

    if (nt > 0) {
        // ---- touch-prefetch into L2 (results discarded in LDS trash) ----
        {
            LDS_AS uint32_t* trash =
                (LDS_AS uint32_t*)(smem + TRASH_OFF + w * 1024);
            for (int t = 0; t < nt; ++t) {           // B: all tiles
                const _Float16* Wp = (t < 8) ? W1 : W2;
                const int koff = (t & 7) * 64;
#pragma unroll
                for (int q = 0; q < 2; ++q)
                    __builtin_amdgcn_global_load_lds(
                        (const GLOBAL_AS uint32_t*)(Wp + boff[q] + koff),
                        trash, 16, 0, 0);
            }
            for (int t = 0; t < 8; ++t) {            // A: pass-1 tiles
                const int koff = t * 64;
#pragma unroll
                for (int q = 0; q < 2; ++q)
                    __builtin_amdgcn_global_load_lds(
                        (const GLOBAL_AS uint32_t*)(A1 + aoff[q] + koff),
                        trash, 16, 0, 0);
            }
            __builtin_amdgcn_sched_barrier(0);   // pin: touches precede ring
        }

        issue(0, 0);
        issue(1, 1);
        int cbuf = 0, ibuf = 2;
        for (int t = 0; t < nt; ++t) {
            if (t < nt - 1) asm volatile("s_waitcnt vmcnt(4)" ::: "memory");
            else            asm volatile("s_waitcnt vmcnt(0)" ::: "memory");
            __builtin_amdgcn_s_barrier();   // all waves' tile-t chunks in LDS
            if (t + 2 < nt) {               // buffer (t+2)%3 = (t-1)%3: its
                issue(t + 2, ibuf);         // reads were consumed last iter
                ibuf = (ibuf == 2) ? 0 : ibuf + 1;
            }
            const char* ab = smem + cbuf * 16384;
            const char* bb = ab + 8192;
#pragma unroll
            for (int ks = 0; ks < 2; ++ks) {
                half8 af[2], bf[2];
#pragma unroll
                for (int f = 0; f < 2; ++f) {
                    const int gg = ks * 4 + (l >> 4);
                    const int m = mw + f * 16 + (l & 15);
                    af[f] = *reinterpret_cast<const half8*>(ab + m * 128 + ((gg ^ (m & 7)) * 16));
                    const int n = nw + f * 16 + (l & 15);
                    bf[f] = *reinterpret_cast<const half8*>(bb + n * 128 + ((gg ^ (n & 7)) * 16));
                }
#pragma unroll
                for (int fm = 0; fm < 2; ++fm)
#pragma unroll
                    for (int fn = 0; fn < 2; ++fn)
                        acc[fm][fn] = __builtin_amdgcn_mfma_f32_16x16x32_f16(
                            af[fm], bf[fn], acc[fm][fn], 0, 0, 0);
            }
            cbuf = (cbuf == 2) ? 0 : cbuf + 1;
        }
        __syncthreads();   // all reads done before smem is reused for Gs
    }

    float* Gs = reinterpret_cast<float*>(smem);   // 16.6KB, fits in ring area
#pragma unroll
    for (int fm = 0; fm < 2; ++fm)
#pragma unroll
        for (int fn = 0; fn < 2; ++fn)
#pragma unroll
            for (int r = 0; r < 4; ++r)
                Gs[(mw + fm * 16 + (l >> 4) * 4 + r) * 65 + nw + fn * 16 + (l & 15)] =
                    acc[fm][fn][r];
    __syncthreads();

    {
        const int em = tid & 63;
        const int ekq = tid >> 6;
        const int brow = m0 + em;
        const int kbase = kc0 + ekq * 4;
        float g4[4][4];
#pragma unroll
        for (int gate = 0; gate < 4; ++gate)
#pragma unroll
            for (int j = 0; j < 4; ++j)
                g4[gate][j] = Gs[em * 65 + gate * 16 + ekq * 4 + j]
                            + bias[gate * H + kbase + j];
        if (Wih != nullptr) {
            float x0, x1, x2, x3;
            if (xl != nullptr) {
                x0 = xl[em * 4 + 0]; x1 = xl[em * 4 + 1];
                x2 = xl[em * 4 + 2]; x3 = xl[em * 4 + 3];
            } else {
                const float* xr = xg + (size_t)brow * xstride;
                x0 = xr[0]; x1 = xr[1]; x2 = xr[2]; x3 = xr[3];
            }
#pragma unroll
            for (int gate = 0; gate < 4; ++gate)
#pragma unroll
                for (int j = 0; j < 4; ++j) {
                    const float* wv = &Wih[(size_t)(gate * H + kbase + j) * 4];
                    g4[gate][j] += x0 * wv[0] + x1 * wv[1] + x2 * wv[2] + x3 * wv[3];
                }
        }
        size_t cidx = (size_t)brow * H + kbase;
        f32x4 cold;
        if (zero_c) { cold[0] = cold[1] = cold[2] = cold[3] = 0.f; }
        else        { cold = *reinterpret_cast<const f32x4*>(&c_st[cidx]); }
        f32x4 cnew;
        _Float16 h4[4];
#pragma unroll
        for (int j = 0; j < 4; ++j) {
            float cn = sigm(g4[1][j]) * cold[j] + sigm(g4[0][j]) * tanhf(g4[2][j]);
            cnew[j] = cn;
            h4[j] = (_Float16)(sigm(g4[3][j]) * tanhf(cn));
        }
        *reinterpret_cast<f32x4*>(&c_st[cidx]) = cnew;
        u64 hbits;
        __builtin_memcpy(&hbits, h4, 8);
        *reinterpret_cast<u64*>(h_out + cidx) = hbits;
        if (pH != nullptr) {
#pragma unroll
            for (int j = 0; j < 4; ++j)
                pH[em * 16 + ekq * 4 + j] = h4[j];
        }
    }
}

// ---------------- encoder: dispatch d = L0(d) || L1(d-1) ----------------
__global__ __launch_bounds__(NTHR)
void enc_step(int d, const float* __restrict__ x,
              const float* __restrict__ eWih0, const float* __restrict__ eb0,
              const float* __restrict__ eb1,
              const _Float16* __restrict__ eWhh0, const _Float16* __restrict__ eWih1,
              const _Float16* __restrict__ eWhh1,
              float* __restrict__ c0, float* __restrict__ c1,
              _Float16* h0a, _Float16* h0b, _Float16* h1a, _Float16* h1b)
{
    __shared__ __align__(16) char smem[SMEM_BYTES];
    const int bx = blockIdx.x;
    const int role = bx >> 9, sub = bx & 511;
    int m0, kc0, ntile;
    sub_map(sub, m0, kc0, ntile);
    _Float16* h0[2] = {h0a, h0b};
    _Float16* h1[2] = {h1a, h1b};

    if (role == 0) {
        const int t = d;
        if (t >= T_SRC) return;
        const _Float16* A1 = (t == 0) ? nullptr : h0[(t - 1) & 1];
        layer_core(smem, A1, eWhh0, nullptr, nullptr, (t == 0) ? 0 : 1, (t == 0) ? 1 : 0,
                   x + (size_t)t * I_DIM, T_SRC * I_DIM, nullptr,
                   eWih0, eb0, c0, h0[t & 1], nullptr, m0, kc0);
    } else {
        const int t = d - 1;
        if (t < 0) return;
        if (t == 0)
            layer_core(smem, h0[0], eWih1, nullptr, nullptr, 1, 1,
                       nullptr, 0, nullptr, nullptr, eb1, c1, h1[0], nullptr, m0, kc0);
        else
            layer_core(smem, h0[t & 1], eWih1, h1[(t - 1) & 1], eWhh1, 2, 0,
                       nullptr, 0, nullptr, nullptr, eb1, c1, h1[t & 1], nullptr, m0, kc0);
    }
}

// ---------------- decoder (r6/r12 structure: fixed-point atomic head) ----------------
__global__ __launch_bounds__(NTHR)
void dec0_step(int t, const float* __restrict__ x,
               const float* __restrict__ dWih0, const float* __restrict__ db0,
               const float* __restrict__ headb,
               const _Float16* __restrict__ dWhh0,
               float* __restrict__ c0,
               _Float16* h0a, _Float16* h0b,
               u64* __restrict__ accA, u64* __restrict__ accB,
               float* __restrict__ outp)
{
    __shared__ __align__(16) char smem[SMEM_BYTES];
    __shared__ float decbuf[64 * 4];
    const int sub = blockIdx.x;
    int m0, kc0, ntile;
    sub_map(sub, m0, kc0, ntile);
    const int tid = threadIdx.x;
    _Float16* h0[2] = {h0a, h0b};

    u64* accCur = (t & 1) ? accB : accA;
    u64* accPrev = (t & 1) ? accA : accB;

    const int row = tid >> 2, o = tid & 3;
    if (ntile == 0)
        accCur[(size_t)(m0 + row) * I_DIM + o] = 0ull;

    const float* xg = nullptr;
    const float* xl = nullptr;
    if (t == 0) {
        xg = x + (size_t)(T_SRC - 1) * I_DIM;
    } else {
        long long v = (long long)accPrev[(size_t)(m0 + row) * I_DIM + o];
        float val = (float)((double)v * (1.0 / 1099511627776.0)) + headb[o];
        decbuf[tid] = val;
        if (ntile == 0)
            outp[((size_t)(m0 + row) * T_TGT + (t - 1)) * I_DIM + o] = val;
        xl = decbuf;
        __syncthreads();
    }

    const _Float16* A1 = (t == 0) ? h0[1] : h0[(t - 1) & 1];
    layer_core(smem, A1, dWhh0, nullptr, nullptr, 1, 0,
               xg, T_SRC * I_DIM, xl, dWih0, db0, c0, h0[t & 1], nullptr, m0, kc0);
}

__global__ __launch_bounds__(NTHR)
void dec1_step(int t, const float* __restrict__ db1,
               const float* __restrict__ headW,
               const _Float16* __restrict__ dWih1, const _Float16* __restrict__ dWhh1,
               float* __restrict__ c1,
               _Float16* h0a, _Float16* h0b, _Float16* h1a, _Float16* h1b,
               u64* __restrict__ accA, u64* __restrict__ accB)
{
    __shared__ __align__(16) char smem[SMEM_BYTES];
    __shared__ _Float16 pH[64 * 16];
    const int sub = blockIdx.x;
    int m0, kc0, ntile;
    sub_map(sub, m0, kc0, ntile);
    const int tid = threadIdx.x;
    _Float16* h0[2] = {h0a, h0b};
    _Float16* h1[2] = {h1a, h1b};

    const _Float16* h1prev = (t == 0) ? h1[1] : h1[(t - 1) & 1];
    layer_core(smem, h0[t & 1], dWih1, h1prev, dWhh1, 2, 0,
               nullptr, 0, nullptr, nullptr, db1, c1, h1[t & 1], pH, m0, kc0);
    __syncthreads();

    u64* accCur = (t & 1) ? accB : accA;
    const int em = tid >> 2, o = tid & 3;
    float s = 0.f;
#pragma unroll
    for (int j = 0; j < 16; ++j)
        s += (float)pH[em * 16 + j] * headW[(size_t)o * H + kc0 + j];
    long long qv = (long long)(s * SCALE_F);
    atomicAdd(accCur + ((size_t)(m0 + em) * I_DIM + o), (u64)qv);
}

__global__ __launch_bounds__(NTHR)
void final_out(const u64* __restrict__ accLast, const float* __restrict__ headb,
               float* __restrict__ outp)
{
    int i = blockIdx.x * blockDim.x + threadIdx.x;
    if (i < B * I_DIM) {
        int b = i >> 2, o = i & 3;
        long long v = (long long)accLast[i];
        float val = (float)((double)v * (1.0 / 1099511627776.0)) + headb[o];
        outp[((size_t)b * T_TGT + (T_TGT - 1)) * I_DIM + o] = val;
    }
}

__global__ void convert6(const float* __restrict__ s0, const float* __restrict__ s1,
                         const float* __restrict__ s2, const float* __restrict__ s3,
                         const float* __restrict__ s4, const float* __restrict__ s5,
                         _Float16* __restrict__ dst)
{
    const int WN4 = (1 << 20) / 4;
    int i = blockIdx.x * blockDim.x + threadIdx.x;
    int stride = gridDim.x * blockDim.x;
    for (; i < 6 * WN4; i += stride) {
        int seg = i / WN4;
        int off = i - seg * WN4;
        const float* sp = seg == 0 ? s0 : seg == 1 ? s1 : seg == 2 ? s2
                        : seg == 3 ? s3 : seg == 4 ? s4 : s5;
        float4 v = reinterpret_cast<const float4*>(sp)[off];
        _Float16 h4o[4] = {(_Float16)v.x, (_Float16)v.y, (_Float16)v.z, (_Float16)v.w};
        u64 bits;
        __builtin_memcpy(&bits, h4o, 8);
        reinterpret_cast<u64*>(dst)[i] = bits;
    }
}

extern "C" void kernel_launch(void* const* d_in, const int* in_sizes, int n_in,
                              void* d_out, int out_size, void* d_ws, size_t ws_size,
                              hipStream_t stream)
{
    const float* x        = (const float*)d_in[0];
    const float* enc_Wih0 = (const float*)d_in[1];
    const float* enc_Whh0 = (const float*)d_in[2];
    const float* enc_b0   = (const float*)d_in[3];
    const float* enc_Wih1 = (const float*)d_in[4];
    const float* enc_Whh1 = (const float*)d_in[5];
    const float* enc_b1   = (const float*)d_in[6];
    const float* dec_Wih0 = (const float*)d_in[7];
    const float* dec_Whh0 = (const float*)d_in[8];
    const float* dec_b0   = (const float*)d_in[9];
    const float* dec_Wih1 = (const float*)d_in[10];
    const float* dec_Whh1 = (const float*)d_in[11];
    const float* dec_b1   = (const float*)d_in[12];
    const float* head_W   = (const float*)d_in[13];
    const float* head_b   = (const float*)d_in[14];
    float* out = (float*)d_out;

    const size_t MB = 1u << 20;
    char* ws = (char*)d_ws;
    float*    c0     = (float*)(ws + 0 * MB);
    float*    c1     = (float*)(ws + 2 * MB);
    _Float16* h0a    = (_Float16*)(ws + 4 * MB);
    _Float16* h0b    = (_Float16*)(ws + 5 * MB);
    _Float16* h1a    = (_Float16*)(ws + 6 * MB);
    _Float16* h1b    = (_Float16*)(ws + 7 * MB);
    u64*      accA   = (u64*)(ws + 8 * MB);
    u64*      accB   = (u64*)(ws + 8 * MB + 65536);
    _Float16* wf16   = (_Float16*)(ws + 9 * MB);

    convert6<<<2048, NTHR, 0, stream>>>(enc_Whh0, enc_Wih1, enc_Whh1,
                                        dec_Whh0, dec_Wih1, dec_Whh1, wf16);
    _Float16* eWhh0f = wf16 + 0 * (1 << 20);
    _Float16* eWih1f = wf16 + 1 * (1 << 20);
    _Float16* eWhh1f = wf16 + 2 * (1 << 20);
    _Float16* dWhh0f = wf16 + 3 * (1 << 20);
    _Float16* dWih1f = wf16 + 4 * (1 << 20);
    _Float16* dWhh1f = wf16 + 5 * (1 << 20);

    // encoder: dispatch d runs L0(d) || L1(d-1)
    for (int d = 0; d <= T_SRC; ++d)
        enc_step<<<1024, NTHR, 0, stream>>>(d, x, enc_Wih0, enc_b0, enc_b1,
                                            eWhh0f, eWih1f, eWhh1f,
                                            c0, c1, h0a, h0b, h1a, h1b);

    // decoder: 2 dispatches per step; head folded into dec1 (fixed-point atomics)
    for (int t = 0; t < T_TGT; ++t) {
        dec0_step<<<512, NTHR, 0, stream>>>(t, x, dec_Wih0, dec_b0, head_b,
                                            dWhh0f, c0, h0a, h0b, accA, accB, out);
        dec1_step<<<512, NTHR, 0, stream>>>(t, dec_b1, head_W, dWih1f, dWhh1f,
                                            c1, h0a, h0b, h1a, h1b, accA, accB);
    }
    final_out<<<(B * I_DIM + NTHR - 1) / NTHR, NTHR, 0, stream>>>(
        (T_TGT - 1) & 1 ? accB : accA, head_b, out);
}

// Round 14
// 1571.790 us; speedup vs baseline: 1.1635x; 1.1635x over previous
//
#include <hip/hip_runtime.h>
#include <math.h>
#include <stdint.h>

#define B 1024
#define H 512
#define T_SRC 50
#define T_TGT 30
#define I_DIM 4
#define NTHR 256

typedef _Float16 half8 __attribute__((ext_vector_type(8)));
typedef float f32x4 __attribute__((ext_vector_type(4)));
typedef unsigned long long u64;

#define GLOBAL_AS __attribute__((address_space(1)))
#define LDS_AS    __attribute__((address_space(3)))

#define SCALE_F 1099511627776.0f          // 2^40 (head fixed-point)
#define SMEM_BYTES 49152                  // 3 x 16KB ring

__device__ __forceinline__ float sigm(float x) { return 1.0f / (1.0f + expf(-x)); }

// XCD-pinned mapping: blocks sharing a weight slice (ntile) land on one XCD
// (empirical bx%8 round-robin; perf heuristic only — correctness unaffected).
__device__ __forceinline__ void sub_map(int sub, int& m0, int& kc0, int& ntile)
{
    const int xcd = sub & 7, j = sub >> 3;      // j in [0,64)
    ntile = xcd * 4 + (j >> 4);                 // [0,32): pinned to xcd
    const int g = j & 15;                       // [0,16)
    m0 = g * 64;
    kc0 = ntile * 16;
}

// ---------------- GEMM+cell core: r6-verified arithmetic + r10-verified
// counted-vmcnt 3-buffer ring (2 tiles in flight across raw s_barrier).
// Per-wave loads/tile = 4; vmcnt retires in order (m135), so vmcnt(4) with
// older stray VMEM ops outstanding still means "tile t fully landed".
__device__ __forceinline__ void layer_core(
    char* smem,
    const _Float16* __restrict__ A1, const _Float16* __restrict__ W1,
    const _Float16* __restrict__ A2, const _Float16* __restrict__ W2,
    int npass, int zero_c,
    const float* __restrict__ xg, int xstride,
    const float* __restrict__ xl,
    const float* __restrict__ Wih,
    const float* __restrict__ bias,
    float* __restrict__ c_st, _Float16* __restrict__ h_out,
    _Float16* pH,
    int m0, int kc0)
{
    const int tid = threadIdx.x;
    const int w = tid >> 6, l = tid & 63;
    const int mw = (w & 1) * 32, nw = (w >> 1) * 32;

    f32x4 acc[2][2] = {};
    const int nt = npass * 8;

    size_t aoff[2], boff[2];
    int ldsw[2];
#pragma unroll
    for (int q = 0; q < 2; ++q) {
        int rowq = (w * 2 + q) * 8 + (l >> 3);
        int gsrc = (l & 7) ^ (rowq & 7);
        aoff[q] = (size_t)(m0 + rowq) * H + gsrc * 8;
        int jg = (rowq >> 4) * H + kc0 + (rowq & 15);
        boff[q] = (size_t)jg * H + gsrc * 8;
        ldsw[q] = (w * 2 + q) * 1024;
    }

    auto issue = [&](int t, int buf) {
        const _Float16* Ap = (t < 8) ? A1 : A2;
        const _Float16* Wp = (t < 8) ? W1 : W2;
        const int koff = (t & 7) * 64;
        char* dbase = smem + buf * 16384;
#pragma unroll
        for (int q = 0; q < 2; ++q) {
            __builtin_amdgcn_global_load_lds(
                (const GLOBAL_AS uint32_t*)(Ap + aoff[q] + koff),
                (LDS_AS uint32_t*)(dbase + ldsw[q]), 16, 0, 0);
            __builtin_amdgcn_global_load_lds(
                (const GLOBAL_AS uint32_t*)(Wp + boff[q] + koff),
                (LDS_AS uint32_t*)(dbase + 8192 + ldsw[q]), 16, 0, 0);
        }
    };

    if (nt > 0) {
        issue(0, 0);
        issue(1, 1);
        int cbuf = 0, ibuf = 2;
        for (int t = 0; t < nt; ++t) {
            if (t < nt - 1) asm volatile("s_waitcnt vmcnt(4)" ::: "memory");
            else            asm volatile("s_waitcnt vmcnt(0)" ::: "memory");
            __builtin_amdgcn_s_barrier();   // all waves' tile-t chunks in LDS
            if (t + 2 < nt) {               // buffer (t+2)%3 = (t-1)%3: its
                issue(t + 2, ibuf);         // reads were consumed last iter
                ibuf = (ibuf == 2) ? 0 : ibuf + 1;
            }
            const char* ab = smem + cbuf * 16384;
            const char* bb = ab + 8192;
#pragma unroll
            for (int ks = 0; ks < 2; ++ks) {
                half8 af[2], bf[2];
#pragma unroll
                for (int f = 0; f < 2; ++f) {
                    const int gg = ks * 4 + (l >> 4);
                    const int m = mw + f * 16 + (l & 15);
                    af[f] = *reinterpret_cast<const half8*>(ab + m * 128 + ((gg ^ (m & 7)) * 16));
                    const int n = nw + f * 16 + (l & 15);
                    bf[f] = *reinterpret_cast<const half8*>(bb + n * 128 + ((gg ^ (n & 7)) * 16));
                }
#pragma unroll
                for (int fm = 0; fm < 2; ++fm)
#pragma unroll
                    for (int fn = 0; fn < 2; ++fn)
                        acc[fm][fn] = __builtin_amdgcn_mfma_f32_16x16x32_f16(
                            af[fm], bf[fn], acc[fm][fn], 0, 0, 0);
            }
            cbuf = (cbuf == 2) ? 0 : cbuf + 1;
        }
        __syncthreads();   // all reads done before smem is reused for Gs
    }

    float* Gs = reinterpret_cast<float*>(smem);   // 16.6KB, fits in 48KB ring
#pragma unroll
    for (int fm = 0; fm < 2; ++fm)
#pragma unroll
        for (int fn = 0; fn < 2; ++fn)
#pragma unroll
            for (int r = 0; r < 4; ++r)
                Gs[(mw + fm * 16 + (l >> 4) * 4 + r) * 65 + nw + fn * 16 + (l & 15)] =
                    acc[fm][fn][r];
    __syncthreads();

    {
        const int em = tid & 63;
        const int ekq = tid >> 6;
        const int brow = m0 + em;
        const int kbase = kc0 + ekq * 4;
        float g4[4][4];
#pragma unroll
        for (int gate = 0; gate < 4; ++gate)
#pragma unroll
            for (int j = 0; j < 4; ++j)
                g4[gate][j] = Gs[em * 65 + gate * 16 + ekq * 4 + j]
                            + bias[gate * H + kbase + j];
        if (Wih != nullptr) {
            float x0, x1, x2, x3;
            if (xl != nullptr) {
                x0 = xl[em * 4 + 0]; x1 = xl[em * 4 + 1];
                x2 = xl[em * 4 + 2]; x3 = xl[em * 4 + 3];
            } else {
                const float* xr = xg + (size_t)brow * xstride;
                x0 = xr[0]; x1 = xr[1]; x2 = xr[2]; x3 = xr[3];
            }
#pragma unroll
            for (int gate = 0; gate < 4; ++gate)
#pragma unroll
                for (int j = 0; j < 4; ++j) {
                    const float* wv = &Wih[(size_t)(gate * H + kbase + j) * 4];
                    g4[gate][j] += x0 * wv[0] + x1 * wv[1] + x2 * wv[2] + x3 * wv[3];
                }
        }
        size_t cidx = (size_t)brow * H + kbase;
        f32x4 cold;
        if (zero_c) { cold[0] = cold[1] = cold[2] = cold[3] = 0.f; }
        else        { cold = *reinterpret_cast<const f32x4*>(&c_st[cidx]); }
        f32x4 cnew;
        _Float16 h4[4];
#pragma unroll
        for (int j = 0; j < 4; ++j) {
            float cn = sigm(g4[1][j]) * cold[j] + sigm(g4[0][j]) * tanhf(g4[2][j]);
            cnew[j] = cn;
            h4[j] = (_Float16)(sigm(g4[3][j]) * tanhf(cn));
        }
        *reinterpret_cast<f32x4*>(&c_st[cidx]) = cnew;
        u64 hbits;
        __builtin_memcpy(&hbits, h4, 8);
        *reinterpret_cast<u64*>(h_out + cidx) = hbits;
        if (pH != nullptr) {
#pragma unroll
            for (int j = 0; j < 4; ++j)
                pH[em * 16 + ekq * 4 + j] = h4[j];
        }
    }
}

// ---------------- encoder: dispatch d = L0(d) || L1(d-1) (r6 structure) ----------------
__global__ __launch_bounds__(NTHR)
void enc_step(int d, const float* __restrict__ x,
              const float* __restrict__ eWih0, const float* __restrict__ eb0,
              const float* __restrict__ eb1,
              const _Float16* __restrict__ eWhh0, const _Float16* __restrict__ eWih1,
              const _Float16* __restrict__ eWhh1,
              float* __restrict__ c0, float* __restrict__ c1,
              _Float16* h0a, _Float16* h0b, _Float16* h1a, _Float16* h1b)
{
    __shared__ __align__(16) char smem[SMEM_BYTES];
    const int bx = blockIdx.x;
    const int role = bx >> 9, sub = bx & 511;
    int m0, kc0, ntile;
    sub_map(sub, m0, kc0, ntile);
    _Float16* h0[2] = {h0a, h0b};
    _Float16* h1[2] = {h1a, h1b};

    if (role == 0) {
        const int t = d;
        if (t >= T_SRC) return;
        const _Float16* A1 = (t == 0) ? nullptr : h0[(t - 1) & 1];
        layer_core(smem, A1, eWhh0, nullptr, nullptr, (t == 0) ? 0 : 1, (t == 0) ? 1 : 0,
                   x + (size_t)t * I_DIM, T_SRC * I_DIM, nullptr,
                   eWih0, eb0, c0, h0[t & 1], nullptr, m0, kc0);
    } else {
        const int t = d - 1;
        if (t < 0) return;
        if (t == 0)
            layer_core(smem, h0[0], eWih1, nullptr, nullptr, 1, 1,
                       nullptr, 0, nullptr, nullptr, eb1, c1, h1[0], nullptr, m0, kc0);
        else
            layer_core(smem, h0[t & 1], eWih1, h1[(t - 1) & 1], eWhh1, 2, 0,
                       nullptr, 0, nullptr, nullptr, eb1, c1, h1[t & 1], nullptr, m0, kc0);
    }
}

// ---------------- decoder (r6 structure: fixed-point atomic head) ----------------
__global__ __launch_bounds__(NTHR)
void dec0_step(int t, const float* __restrict__ x,
               const float* __restrict__ dWih0, const float* __restrict__ db0,
               const float* __restrict__ headb,
               const _Float16* __restrict__ dWhh0,
               float* __restrict__ c0,
               _Float16* h0a, _Float16* h0b,
               u64* __restrict__ accA, u64* __restrict__ accB,
               float* __restrict__ outp)
{
    __shared__ __align__(16) char smem[SMEM_BYTES];
    __shared__ float decbuf[64 * 4];
    const int sub = blockIdx.x;
    int m0, kc0, ntile;
    sub_map(sub, m0, kc0, ntile);
    const int tid = threadIdx.x;
    _Float16* h0[2] = {h0a, h0b};

    u64* accCur = (t & 1) ? accB : accA;
    u64* accPrev = (t & 1) ? accA : accB;

    const int row = tid >> 2, o = tid & 3;
    if (ntile == 0)
        accCur[(size_t)(m0 + row) * I_DIM + o] = 0ull;

    const float* xg = nullptr;
    const float* xl = nullptr;
    if (t == 0) {
        xg = x + (size_t)(T_SRC - 1) * I_DIM;
    } else {
        long long v = (long long)accPrev[(size_t)(m0 + row) * I_DIM + o];
        float val = (float)((double)v * (1.0 / 1099511627776.0)) + headb[o];
        decbuf[tid] = val;
        if (ntile == 0)
            outp[((size_t)(m0 + row) * T_TGT + (t - 1)) * I_DIM + o] = val;
        xl = decbuf;
        __syncthreads();
    }

    const _Float16* A1 = (t == 0) ? h0[1] : h0[(t - 1) & 1];
    layer_core(smem, A1, dWhh0, nullptr, nullptr, 1, 0,
               xg, T_SRC * I_DIM, xl, dWih0, db0, c0, h0[t & 1], nullptr, m0, kc0);
}

__global__ __launch_bounds__(NTHR)
void dec1_step(int t, const float* __restrict__ db1,
               const float* __restrict__ headW,
               const _Float16* __restrict__ dWih1, const _Float16* __restrict__ dWhh1,
               float* __restrict__ c1,
               _Float16* h0a, _Float16* h0b, _Float16* h1a, _Float16* h1b,
               u64* __restrict__ accA, u64* __restrict__ accB)
{
    __shared__ __align__(16) char smem[SMEM_BYTES];
    __shared__ _Float16 pH[64 * 16];
    const int sub = blockIdx.x;
    int m0, kc0, ntile;
    sub_map(sub, m0, kc0, ntile);
    const int tid = threadIdx.x;
    _Float16* h0[2] = {h0a, h0b};
    _Float16* h1[2] = {h1a, h1b};

    const _Float16* h1prev = (t == 0) ? h1[1] : h1[(t - 1) & 1];
    layer_core(smem, h0[t & 1], dWih1, h1prev, dWhh1, 2, 0,
               nullptr, 0, nullptr, nullptr, db1, c1, h1[t & 1], pH, m0, kc0);
    __syncthreads();

    u64* accCur = (t & 1) ? accB : accA;
    const int em = tid >> 2, o = tid & 3;
    float s = 0.f;
#pragma unroll
    for (int j = 0; j < 16; ++j)
        s += (float)pH[em * 16 + j] * headW[(size_t)o * H + kc0 + j];
    long long qv = (long long)(s * SCALE_F);
    atomicAdd(accCur + ((size_t)(m0 + em) * I_DIM + o), (u64)qv);
}

__global__ __launch_bounds__(NTHR)
void final_out(const u64* __restrict__ accLast, const float* __restrict__ headb,
               float* __restrict__ outp)
{
    int i = blockIdx.x * blockDim.x + threadIdx.x;
    if (i < B * I_DIM) {
        int b = i >> 2, o = i & 3;
        long long v = (long long)accLast[i];
        float val = (float)((double)v * (1.0 / 1099511627776.0)) + headb[o];
        outp[((size_t)b * T_TGT + (T_TGT - 1)) * I_DIM + o] = val;
    }
}

__global__ void convert6(const float* __restrict__ s0, const float* __restrict__ s1,
                         const float* __restrict__ s2, const float* __restrict__ s3,
                         const float* __restrict__ s4, const float* __restrict__ s5,
                         _Float16* __restrict__ dst)
{
    const int WN4 = (1 << 20) / 4;
    int i = blockIdx.x * blockDim.x + threadIdx.x;
    int stride = gridDim.x * blockDim.x;
    for (; i < 6 * WN4; i += stride) {
        int seg = i / WN4;
        int off = i - seg * WN4;
        const float* sp = seg == 0 ? s0 : seg == 1 ? s1 : seg == 2 ? s2
                        : seg == 3 ? s3 : seg == 4 ? s4 : s5;
        float4 v = reinterpret_cast<const float4*>(sp)[off];
        _Float16 h4o[4] = {(_Float16)v.x, (_Float16)v.y, (_Float16)v.z, (_Float16)v.w};
        u64 bits;
        __builtin_memcpy(&bits, h4o, 8);
        reinterpret_cast<u64*>(dst)[i] = bits;
    }
}

extern "C" void kernel_launch(void* const* d_in, const int* in_sizes, int n_in,
                              void* d_out, int out_size, void* d_ws, size_t ws_size,
                              hipStream_t stream)
{
    const float* x        = (const float*)d_in[0];
    const float* enc_Wih0 = (const float*)d_in[1];
    const float* enc_Whh0 = (const float*)d_in[2];
    const float* enc_b0   = (const float*)d_in[3];
    const float* enc_Wih1 = (const float*)d_in[4];
    const float* enc_Whh1 = (const float*)d_in[5];
    const float* enc_b1   = (const float*)d_in[6];
    const float* dec_Wih0 = (const float*)d_in[7];
    const float* dec_Whh0 = (const float*)d_in[8];
    const float* dec_b0   = (const float*)d_in[9];
    const float* dec_Wih1 = (const float*)d_in[10];
    const float* dec_Whh1 = (const float*)d_in[11];
    const float* dec_b1   = (const float*)d_in[12];
    const float* head_W   = (const float*)d_in[13];
    const float* head_b   = (const float*)d_in[14];
    float* out = (float*)d_out;

    const size_t MB = 1u << 20;
    char* ws = (char*)d_ws;
    float*    c0     = (float*)(ws + 0 * MB);
    float*    c1     = (float*)(ws + 2 * MB);
    _Float16* h0a    = (_Float16*)(ws + 4 * MB);
    _Float16* h0b    = (_Float16*)(ws + 5 * MB);
    _Float16* h1a    = (_Float16*)(ws + 6 * MB);
    _Float16* h1b    = (_Float16*)(ws + 7 * MB);
    u64*      accA   = (u64*)(ws + 8 * MB);
    u64*      accB   = (u64*)(ws + 8 * MB + 65536);
    _Float16* wf16   = (_Float16*)(ws + 9 * MB);

    convert6<<<2048, NTHR, 0, stream>>>(enc_Whh0, enc_Wih1, enc_Whh1,
                                        dec_Whh0, dec_Wih1, dec_Whh1, wf16);
    _Float16* eWhh0f = wf16 + 0 * (1 << 20);
    _Float16* eWih1f = wf16 + 1 * (1 << 20);
    _Float16* eWhh1f = wf16 + 2 * (1 << 20);
    _Float16* dWhh0f = wf16 + 3 * (1 << 20);
    _Float16* dWih1f = wf16 + 4 * (1 << 20);
    _Float16* dWhh1f = wf16 + 5 * (1 << 20);

    // encoder: dispatch d runs L0(d) || L1(d-1)
    for (int d = 0; d <= T_SRC; ++d)
        enc_step<<<1024, NTHR, 0, stream>>>(d, x, enc_Wih0, enc_b0, enc_b1,
                                            eWhh0f, eWih1f, eWhh1f,
                                            c0, c1, h0a, h0b, h1a, h1b);

    // decoder: 2 dispatches per step; head folded into dec1 (fixed-point atomics)
    for (int t = 0; t < T_TGT; ++t) {
        dec0_step<<<512, NTHR, 0, stream>>>(t, x, dec_Wih0, dec_b0, head_b,
                                            dWhh0f, c0, h0a, h0b, accA, accB, out);
        dec1_step<<<512, NTHR, 0, stream>>>(t, dec_b1, head_W, dWih1f, dWhh1f,
                                            c1, h0a, h0b, h1a, h1b, accA, accB);
    }
    final_out<<<(B * I_DIM + NTHR - 1) / NTHR, NTHR, 0, stream>>>(
        (T_TGT - 1) & 1 ? accB : accA, head_b, out);
}

// Round 15
// 1552.880 us; speedup vs baseline: 1.1777x; 1.0122x over previous
//
#include <hip/hip_runtime.h>
#include <math.h>
#include <stdint.h>

#define B 1024
#define H 512
#define T_SRC 50
#define T_TGT 30
#define I_DIM 4
#define NTHR 256

typedef _Float16 half8 __attribute__((ext_vector_type(8)));
typedef float f32x4 __attribute__((ext_vector_type(4)));
typedef unsigned long long u64;

#define GLOBAL_AS __attribute__((address_space(1)))
#define LDS_AS    __attribute__((address_space(3)))

#define SCALE_F 1099511627776.0f          // 2^40 (head fixed-point)
#define B_RING 24576                      // A: 3x8KB at 0; B: 2x8KB at 24576
#define SMEM_BYTES 40960                  // 4 blocks/CU (160KB/40KB exactly)

__device__ __forceinline__ float sigm(float x) { return 1.0f / (1.0f + expf(-x)); }

// XCD-pinned mapping (r12-verified): blocks sharing a weight slice (ntile)
// land on one XCD (bx%8 round-robin heuristic; correctness unaffected).
__device__ __forceinline__ void sub_map(int sub, int& m0, int& kc0, int& ntile)
{
    const int xcd = sub & 7, j = sub >> 3;      // j in [0,64)
    ntile = xcd * 4 + (j >> 4);                 // [0,32): pinned to xcd
    const int g = j & 15;                       // [0,16)
    m0 = g * 64;
    kc0 = ntile * 16;
}

// ---------------- GEMM+cell core: r12-verified arithmetic; split-ring
// staging: A-ring-3 (L3-cold h: 2-tile lookahead) + B-ring-2 (L2-hot
// weights after XCD pinning: 1-tile lookahead) = 40KB -> 4 blocks/CU.
// Per iter u: wait vmcnt(2) [only A(u+1)'s 2 loads may remain; in-order
// retirement m135] -> s_barrier -> issue B(u+1),A(u+2) [both target the
// buffers read in iter u-1, drained by this barrier] -> MFMA tile u.
__device__ __forceinline__ void layer_core(
    char* smem,
    const _Float16* __restrict__ A1, const _Float16* __restrict__ W1,
    const _Float16* __restrict__ A2, const _Float16* __restrict__ W2,
    int npass, int zero_c,
    const float* __restrict__ xg, int xstride,
    const float* __restrict__ xl,
    const float* __restrict__ Wih,
    const float* __restrict__ bias,
    float* __restrict__ c_st, _Float16* __restrict__ h_out,
    _Float16* pH,
    int m0, int kc0)
{
    const int tid = threadIdx.x;
    const int w = tid >> 6, l = tid & 63;
    const int mw = (w & 1) * 32, nw = (w >> 1) * 32;

    f32x4 acc[2][2] = {};
    const int nt = npass * 8;

    size_t aoff[2], boff[2];
    int ldsw[2];
#pragma unroll
    for (int q = 0; q < 2; ++q) {
        int rowq = (w * 2 + q) * 8 + (l >> 3);
        int gsrc = (l & 7) ^ (rowq & 7);
        aoff[q] = (size_t)(m0 + rowq) * H + gsrc * 8;
        int jg = (rowq >> 4) * H + kc0 + (rowq & 15);
        boff[q] = (size_t)jg * H + gsrc * 8;
        ldsw[q] = (w * 2 + q) * 1024;
    }

    auto issueA = [&](int t, int slot) {
        const _Float16* Ap = (t < 8) ? A1 : A2;
        const int koff = (t & 7) * 64;
        char* dbase = smem + slot * 8192;
#pragma unroll
        for (int q = 0; q < 2; ++q)
            __builtin_amdgcn_global_load_lds(
                (const GLOBAL_AS uint32_t*)(Ap + aoff[q] + koff),
                (LDS_AS uint32_t*)(dbase + ldsw[q]), 16, 0, 0);
    };
    auto issueB = [&](int t, int slot) {
        const _Float16* Wp = (t < 8) ? W1 : W2;
        const int koff = (t & 7) * 64;
        char* dbase = smem + B_RING + slot * 8192;
#pragma unroll
        for (int q = 0; q < 2; ++q)
            __builtin_amdgcn_global_load_lds(
                (const GLOBAL_AS uint32_t*)(Wp + boff[q] + koff),
                (LDS_AS uint32_t*)(dbase + ldsw[q]), 16, 0, 0);
    };

    if (nt > 0) {
        // prologue: A0,B0,A1 (queue order matches steady-state counting)
        issueA(0, 0);
        issueB(0, 0);
        issueA(1, 1);
        int aslot = 2;   // next A slot (t+2)%3
        for (int t = 0; t < nt; ++t) {
            if (t < nt - 1) asm volatile("s_waitcnt vmcnt(2)" ::: "memory");
            else            asm volatile("s_waitcnt vmcnt(0)" ::: "memory");
            __builtin_amdgcn_s_barrier();   // all waves' tile-t chunks in LDS
            if (t + 1 < nt) issueB(t + 1, (t + 1) & 1);
            if (t + 2 < nt) {
                issueA(t + 2, aslot);
                aslot = (aslot == 2) ? 0 : aslot + 1;
            }
            const char* ab = smem + (t % 3) * 8192;
            const char* bb = smem + B_RING + (t & 1) * 8192;
#pragma unroll
            for (int ks = 0; ks < 2; ++ks) {
                half8 af[2], bf[2];
#pragma unroll
                for (int f = 0; f < 2; ++f) {
                    const int gg = ks * 4 + (l >> 4);
                    const int m = mw + f * 16 + (l & 15);
                    af[f] = *reinterpret_cast<const half8*>(ab + m * 128 + ((gg ^ (m & 7)) * 16));
                    const int n = nw + f * 16 + (l & 15);
                    bf[f] = *reinterpret_cast<const half8*>(bb + n * 128 + ((gg ^ (n & 7)) * 16));
                }
#pragma unroll
                for (int fm = 0; fm < 2; ++fm)
#pragma unroll
                    for (int fn = 0; fn < 2; ++fn)
                        acc[fm][fn] = __builtin_amdgcn_mfma_f32_16x16x32_f16(
                            af[fm], bf[fn], acc[fm][fn], 0, 0, 0);
            }
        }
        __syncthreads();   // all reads done before smem is reused for Gs
    }

    float* Gs = reinterpret_cast<float*>(smem);   // 16.6KB overlay
#pragma unroll
    for (int fm = 0; fm < 2; ++fm)
#pragma unroll
        for (int fn = 0; fn < 2; ++fn)
#pragma unroll
            for (int r = 0; r < 4; ++r)
                Gs[(mw + fm * 16 + (l >> 4) * 4 + r) * 65 + nw + fn * 16 + (l & 15)] =
                    acc[fm][fn][r];
    __syncthreads();

    {
        const int em = tid & 63;
        const int ekq = tid >> 6;
        const int brow = m0 + em;
        const int kbase = kc0 + ekq * 4;
        float g4[4][4];
#pragma unroll
        for (int gate = 0; gate < 4; ++gate)
#pragma unroll
            for (int j = 0; j < 4; ++j)
                g4[gate][j] = Gs[em * 65 + gate * 16 + ekq * 4 + j]
                            + bias[gate * H + kbase + j];
        if (Wih != nullptr) {
            float x0, x1, x2, x3;
            if (xl != nullptr) {
                x0 = xl[em * 4 + 0]; x1 = xl[em * 4 + 1];
                x2 = xl[em * 4 + 2]; x3 = xl[em * 4 + 3];
            } else {
                const float* xr = xg + (size_t)brow * xstride;
                x0 = xr[0]; x1 = xr[1]; x2 = xr[2]; x3 = xr[3];
            }
#pragma unroll
            for (int gate = 0; gate < 4; ++gate)
#pragma unroll
                for (int j = 0; j < 4; ++j) {
                    const float* wv = &Wih[(size_t)(gate * H + kbase + j) * 4];
                    g4[gate][j] += x0 * wv[0] + x1 * wv[1] + x2 * wv[2] + x3 * wv[3];
                }
        }
        size_t cidx = (size_t)brow * H + kbase;
        f32x4 cold;
        if (zero_c) { cold[0] = cold[1] = cold[2] = cold[3] = 0.f; }
        else        { cold = *reinterpret_cast<const f32x4*>(&c_st[cidx]); }
        f32x4 cnew;
        _Float16 h4[4];
#pragma unroll
        for (int j = 0; j < 4; ++j) {
            float cn = sigm(g4[1][j]) * cold[j] + sigm(g4[0][j]) * tanhf(g4[2][j]);
            cnew[j] = cn;
            h4[j] = (_Float16)(sigm(g4[3][j]) * tanhf(cn));
        }
        *reinterpret_cast<f32x4*>(&c_st[cidx]) = cnew;
        u64 hbits;
        __builtin_memcpy(&hbits, h4, 8);
        *reinterpret_cast<u64*>(h_out + cidx) = hbits;
        if (pH != nullptr) {
#pragma unroll
            for (int j = 0; j < 4; ++j)
                pH[em * 16 + ekq * 4 + j] = h4[j];
        }
    }
}

// ---------------- encoder: dispatch d = L0(d) || L1(d-1) ----------------
__global__ __launch_bounds__(NTHR)
void enc_step(int d, const float* __restrict__ x,
              const float* __restrict__ eWih0, const float* __restrict__ eb0,
              const float* __restrict__ eb1,
              const _Float16* __restrict__ eWhh0, const _Float16* __restrict__ eWih1,
              const _Float16* __restrict__ eWhh1,
              float* __restrict__ c0, float* __restrict__ c1,
              _Float16* h0a, _Float16* h0b, _Float16* h1a, _Float16* h1b)
{
    __shared__ __align__(16) char smem[SMEM_BYTES];
    const int bx = blockIdx.x;
    const int role = bx >> 9, sub = bx & 511;
    int m0, kc0, ntile;
    sub_map(sub, m0, kc0, ntile);
    _Float16* h0[2] = {h0a, h0b};
    _Float16* h1[2] = {h1a, h1b};

    if (role == 0) {
        const int t = d;
        if (t >= T_SRC) return;
        const _Float16* A1 = (t == 0) ? nullptr : h0[(t - 1) & 1];
        layer_core(smem, A1, eWhh0, nullptr, nullptr, (t == 0) ? 0 : 1, (t == 0) ? 1 : 0,
                   x + (size_t)t * I_DIM, T_SRC * I_DIM, nullptr,
                   eWih0, eb0, c0, h0[t & 1], nullptr, m0, kc0);
    } else {
        const int t = d - 1;
        if (t < 0) return;
        if (t == 0)
            layer_core(smem, h0[0], eWih1, nullptr, nullptr, 1, 1,
                       nullptr, 0, nullptr, nullptr, eb1, c1, h1[0], nullptr, m0, kc0);
        else
            layer_core(smem, h0[t & 1], eWih1, h1[(t - 1) & 1], eWhh1, 2, 0,
                       nullptr, 0, nullptr, nullptr, eb1, c1, h1[t & 1], nullptr, m0, kc0);
    }
}

// ---------------- decoder (r6/r12 structure: fixed-point atomic head) ----------------
__global__ __launch_bounds__(NTHR)
void dec0_step(int t, const float* __restrict__ x,
               const float* __restrict__ dWih0, const float* __restrict__ db0,
               const float* __restrict__ headb,
               const _Float16* __restrict__ dWhh0,
               float* __restrict__ c0,
               _Float16* h0a, _Float16* h0b,
               u64* __restrict__ accA, u64* __restrict__ accB,
               float* __restrict__ outp)
{
    __shared__ __align__(16) char smem[SMEM_BYTES];
    __shared__ float decbuf[64 * 4];
    const int sub = blockIdx.x;
    int m0, kc0, ntile;
    sub_map(sub, m0, kc0, ntile);
    const int tid = threadIdx.x;
    _Float16* h0[2] = {h0a, h0b};

    u64* accCur = (t & 1) ? accB : accA;
    u64* accPrev = (t & 1) ? accA : accB;

    const int row = tid >> 2, o = tid & 3;
    if (ntile == 0)
        accCur[(size_t)(m0 + row) * I_DIM + o] = 0ull;

    const float* xg = nullptr;
    const float* xl = nullptr;
    if (t == 0) {
        xg = x + (size_t)(T_SRC - 1) * I_DIM;
    } else {
        long long v = (long long)accPrev[(size_t)(m0 + row) * I_DIM + o];
        float val = (float)((double)v * (1.0 / 1099511627776.0)) + headb[o];
        decbuf[tid] = val;
        if (ntile == 0)
            outp[((size_t)(m0 + row) * T_TGT + (t - 1)) * I_DIM + o] = val;
        xl = decbuf;
        __syncthreads();
    }

    const _Float16* A1 = (t == 0) ? h0[1] : h0[(t - 1) & 1];
    layer_core(smem, A1, dWhh0, nullptr, nullptr, 1, 0,
               xg, T_SRC * I_DIM, xl, dWih0, db0, c0, h0[t & 1], nullptr, m0, kc0);
}

__global__ __launch_bounds__(NTHR)
void dec1_step(int t, const float* __restrict__ db1,
               const float* __restrict__ headW,
               const _Float16* __restrict__ dWih1, const _Float16* __restrict__ dWhh1,
               float* __restrict__ c1,
               _Float16* h0a, _Float16* h0b, _Float16* h1a, _Float16* h1b,
               u64* __restrict__ accA, u64* __restrict__ accB)
{
    __shared__ __align__(16) char smem[SMEM_BYTES];
    __shared__ _Float16 pH[64 * 16];
    const int sub = blockIdx.x;
    int m0, kc0, ntile;
    sub_map(sub, m0, kc0, ntile);
    const int tid = threadIdx.x;
    _Float16* h0[2] = {h0a, h0b};
    _Float16* h1[2] = {h1a, h1b};

    const _Float16* h1prev = (t == 0) ? h1[1] : h1[(t - 1) & 1];
    layer_core(smem, h0[t & 1], dWih1, h1prev, dWhh1, 2, 0,
               nullptr, 0, nullptr, nullptr, db1, c1, h1[t & 1], pH, m0, kc0);
    __syncthreads();

    u64* accCur = (t & 1) ? accB : accA;
    const int em = tid >> 2, o = tid & 3;
    float s = 0.f;
#pragma unroll
    for (int j = 0; j < 16; ++j)
        s += (float)pH[em * 16 + j] * headW[(size_t)o * H + kc0 + j];
    long long qv = (long long)(s * SCALE_F);
    atomicAdd(accCur + ((size_t)(m0 + em) * I_DIM + o), (u64)qv);
}

__global__ __launch_bounds__(NTHR)
void final_out(const u64* __restrict__ accLast, const float* __restrict__ headb,
               float* __restrict__ outp)
{
    int i = blockIdx.x * blockDim.x + threadIdx.x;
    if (i < B * I_DIM) {
        int b = i >> 2, o = i & 3;
        long long v = (long long)accLast[i];
        float val = (float)((double)v * (1.0 / 1099511627776.0)) + headb[o];
        outp[((size_t)b * T_TGT + (T_TGT - 1)) * I_DIM + o] = val;
    }
}

__global__ void convert6(const float* __restrict__ s0, const float* __restrict__ s1,
                         const float* __restrict__ s2, const float* __restrict__ s3,
                         const float* __restrict__ s4, const float* __restrict__ s5,
                         _Float16* __restrict__ dst)
{
    const int WN4 = (1 << 20) / 4;
    int i = blockIdx.x * blockDim.x + threadIdx.x;
    int stride = gridDim.x * blockDim.x;
    for (; i < 6 * WN4; i += stride) {
        int seg = i / WN4;
        int off = i - seg * WN4;
        const float* sp = seg == 0 ? s0 : seg == 1 ? s1 : seg == 2 ? s2
                        : seg == 3 ? s3 : seg == 4 ? s4 : s5;
        float4 v = reinterpret_cast<const float4*>(sp)[off];
        _Float16 h4o[4] = {(_Float16)v.x, (_Float16)v.y, (_Float16)v.z, (_Float16)v.w};
        u64 bits;
        __builtin_memcpy(&bits, h4o, 8);
        reinterpret_cast<u64*>(dst)[i] = bits;
    }
}

extern "C" void kernel_launch(void* const* d_in, const int* in_sizes, int n_in,
                              void* d_out, int out_size, void* d_ws, size_t ws_size,
                              hipStream_t stream)
{
    const float* x        = (const float*)d_in[0];
    const float* enc_Wih0 = (const float*)d_in[1];
    const float* enc_Whh0 = (const float*)d_in[2];
    const float* enc_b0   = (const float*)d_in[3];
    const float* enc_Wih1 = (const float*)d_in[4];
    const float* enc_Whh1 = (const float*)d_in[5];
    const float* enc_b1   = (const float*)d_in[6];
    const float* dec_Wih0 = (const float*)d_in[7];
    const float* dec_Whh0 = (const float*)d_in[8];
    const float* dec_b0   = (const float*)d_in[9];
    const float* dec_Wih1 = (const float*)d_in[10];
    const float* dec_Whh1 = (const float*)d_in[11];
    const float* dec_b1   = (const float*)d_in[12];
    const float* head_W   = (const float*)d_in[13];
    const float* head_b   = (const float*)d_in[14];
    float* out = (float*)d_out;

    const size_t MB = 1u << 20;
    char* ws = (char*)d_ws;
    float*    c0     = (float*)(ws + 0 * MB);
    float*    c1     = (float*)(ws + 2 * MB);
    _Float16* h0a    = (_Float16*)(ws + 4 * MB);
    _Float16* h0b    = (_Float16*)(ws + 5 * MB);
    _Float16* h1a    = (_Float16*)(ws + 6 * MB);
    _Float16* h1b    = (_Float16*)(ws + 7 * MB);
    u64*      accA   = (u64*)(ws + 8 * MB);
    u64*      accB   = (u64*)(ws + 8 * MB + 65536);
    _Float16* wf16   = (_Float16*)(ws + 9 * MB);

    convert6<<<2048, NTHR, 0, stream>>>(enc_Whh0, enc_Wih1, enc_Whh1,
                                        dec_Whh0, dec_Wih1, dec_Whh1, wf16);
    _Float16* eWhh0f = wf16 + 0 * (1 << 20);
    _Float16* eWih1f = wf16 + 1 * (1 << 20);
    _Float16* eWhh1f = wf16 + 2 * (1 << 20);
    _Float16* dWhh0f = wf16 + 3 * (1 << 20);
    _Float16* dWih1f = wf16 + 4 * (1 << 20);
    _Float16* dWhh1f = wf16 + 5 * (1 << 20);

    // encoder: dispatch d runs L0(d) || L1(d-1)
    for (int d = 0; d <= T_SRC; ++d)
        enc_step<<<1024, NTHR, 0, stream>>>(d, x, enc_Wih0, enc_b0, enc_b1,
                                            eWhh0f, eWih1f, eWhh1f,
                                            c0, c1, h0a, h0b, h1a, h1b);

    // decoder: 2 dispatches per step; head folded into dec1 (fixed-point atomics)
    for (int t = 0; t < T_TGT; ++t) {
        dec0_step<<<512, NTHR, 0, stream>>>(t, x, dec_Wih0, dec_b0, head_b,
                                            dWhh0f, c0, h0a, h0b, accA, accB, out);
        dec1_step<<<512, NTHR, 0, stream>>>(t, dec_b1, head_W, dWih1f, dWhh1f,
                                            c1, h0a, h0b, h1a, h1b, accA, accB);
    }
    final_out<<<(B * I_DIM + NTHR - 1) / NTHR, NTHR, 0, stream>>>(
        (T_TGT - 1) & 1 ? accB : accA, head_b, out);
}